// Round 7
// baseline (819.354 us; speedup 1.0000x reference)
//
#include <hip/hip_runtime.h>
#include <hip/hip_bf16.h>
#include <cmath>

// CapsNet forward. conv2 via split-bf16 MFMA (3-product: ah*bh + al*bh + ah*bl),
// conv1 fused fp32 on VALU, SOFTWARE-PIPELINED:
//   block = 1 image x 256 co (512 thr, 8 waves, grid 256).
//   While B(k) streams 81 taps of MFMA over LDS chunk k, the same waves compute
//   conv1 chunk k+1 into registers (one ky-slice per B ky-iteration); regs are
//   flushed to LDS between barriers. Depth-1 prefetch on A-frags and weights.
// LDS c1 row stride 40 shorts (bank-period-8, conflict-free b128 groups).
// ws (bytes): whi 10,616,832 | wlo 10,616,832 | xcaps 9,437,184 = 30.7 MB

typedef float f32x4 __attribute__((ext_vector_type(4)));
typedef short s16x8 __attribute__((ext_vector_type(8)));

static __device__ __forceinline__ short f2bf(float x) {
  __hip_bfloat16 h = __float2bfloat16(x);
  return *reinterpret_cast<short*>(&h);
}
static __device__ __forceinline__ float bf2f(short s) {
  __hip_bfloat16 h;
  *reinterpret_cast<short*>(&h) = s;
  return __bfloat162float(h);
}

// ---------------- w2 split + transpose: whi/wlo[tap][co][ci] ----------------
__global__ __launch_bounds__(256) void prep_w2(const float* __restrict__ w2,
                                               short* __restrict__ whi,
                                               short* __restrict__ wlo) {
  const int co = blockIdx.x;
  const int ci = threadIdx.x;
  const float* src = w2 + ((size_t)co * 256 + ci) * 81;  // contiguous taps
  for (int tap = 0; tap < 81; ++tap) {
    const float x = src[tap];
    const short hi = f2bf(x);
    const short lo = f2bf(x - bf2f(hi));
    const size_t idx = ((size_t)tap * 256 + co) * 256 + ci;  // ci coalesced
    whi[idx] = hi;
    wlo[idx] = lo;
  }
}

// one ky-slice of a conv1 output row: acc[0..19] += w1[ch][ky][:] * img row
static __device__ __forceinline__ void c1_slice(const float* __restrict__ simg,
                                                const float* __restrict__ w1g,
                                                int ch, int y, int ky,
                                                float* __restrict__ acc) {
  float rr[28];
#pragma unroll
  for (int q = 0; q < 7; ++q)
    *(float4*)&rr[q * 4] = *(const float4*)&simg[(y + ky) * 36 + q * 4];
  const float* wr = w1g + ch * 81 + ky * 9;
#pragma unroll
  for (int kx = 0; kx < 9; ++kx) {
    const float w = wr[kx];
#pragma unroll
    for (int x = 0; x < 20; ++x) acc[x] = fmaf(w, rr[x + kx], acc[x]);
  }
}

static __device__ __forceinline__ void store_c1(short* __restrict__ c1hi,
                                                short* __restrict__ c1lo,
                                                int ci, int y,
                                                const float* __restrict__ acc) {
  short* hp = &c1hi[(y * 20) * 40 + ci];
  short* lp = &c1lo[(y * 20) * 40 + ci];
#pragma unroll
  for (int x = 0; x < 20; ++x) {
    const float v = fmaxf(acc[x], 0.f);
    const short hi = f2bf(v);
    hp[x * 40] = hi;
    lp[x * 40] = f2bf(v - bf2f(hi));
  }
}

// ---------------- conv1 + conv2, pipelined ----------------
__global__ __launch_bounds__(512) void conv2_mfma(
    const float* __restrict__ data, const float* __restrict__ w1,
    const float* __restrict__ b1, const short* __restrict__ whi,
    const short* __restrict__ wlo, const float* __restrict__ b2,
    float* __restrict__ xcaps) {
  const int t = threadIdx.x;
  const int b = blockIdx.x;
  const int lane = t & 63;
  const int wv = t >> 6;  // wave 0..7

  __shared__ float simg[28 * 36];   // image rows padded to 36 floats
  __shared__ short c1hi[400 * 40];  // [pos][ci 0..31, pad to 40]
  __shared__ short c1lo[400 * 40];

  for (int i = t; i < 784; i += 512)
    simg[(i / 28) * 36 + (i % 28)] = data[b * 784 + i];

  const int r16 = lane & 15;  // A row (M) / B col (N) / D col
  const int kg = lane >> 4;   // k-group: k = kg*8 + i

  // A-fragment bases for 3 M-tiles (pad rows clamped to pos 35 -> broadcast)
  int base0[3];
#pragma unroll
  for (int m = 0; m < 3; ++m) {
    int pos = m * 16 + r16;
    if (pos > 35) pos = 35;
    const int oy = pos / 6, ox = pos % 6;
    base0[m] = (oy * 40 + ox * 2) * 40 + kg * 8;  // shorts
  }
  // B-fragment offsets: wave wv covers co [32wv, 32wv+32)
  int boff[2], con[2];
  float bias[2];
#pragma unroll
  for (int j = 0; j < 2; ++j) {
    const int co = wv * 32 + j * 16 + r16;
    con[j] = co;
    boff[j] = co * 256 + kg * 8;
    bias[j] = b2[co];
  }

  // pipeline conv1 tasks: task0 = (ci0, y0), task1 = (ci0, y0+16) for t<128
  const int ci0 = t & 31;
  const int y0 = t >> 5;  // 0..15
  const bool has1 = (t < 128);

  const f32x4 vzero = {0.f, 0.f, 0.f, 0.f};
  f32x4 acc[3][2];
#pragma unroll
  for (int m = 0; m < 3; ++m)
#pragma unroll
    for (int j = 0; j < 2; ++j) acc[m][j] = vzero;

  float accA0[20], accA1[20];

  __syncthreads();  // simg ready
  // ---- prologue: conv1 chunk 0 -> LDS ----
  {
    const float bz = b1[ci0];
#pragma unroll
    for (int x = 0; x < 20; ++x) accA0[x] = bz;
    for (int ky = 0; ky < 9; ++ky) c1_slice(simg, w1, ci0, y0, ky, accA0);
    store_c1(c1hi, c1lo, ci0, y0, accA0);
    if (has1) {
#pragma unroll
      for (int x = 0; x < 20; ++x) accA1[x] = bz;
      for (int ky = 0; ky < 9; ++ky) c1_slice(simg, w1, ci0, y0 + 16, ky, accA1);
      store_c1(c1hi, c1lo, ci0, y0 + 16, accA1);
    }
  }
  __syncthreads();

  for (int k = 0; k < 8; ++k) {
    const bool doA = (k < 7);
    const int chA = (k + 1) * 32 + ci0;
    if (doA) {
      const float bz = b1[chA];
#pragma unroll
      for (int x = 0; x < 20; ++x) { accA0[x] = bz; accA1[x] = bz; }
    }
    for (int ky = 0; ky < 9; ++ky) {
      // ---- interleaved conv1 slice for chunk k+1 (pure VALU) ----
      if (doA) {
        c1_slice(simg, w1, chA, y0, ky, accA0);
        if (has1) c1_slice(simg, w1, chA, y0 + 16, ky, accA1);
      }
      // ---- B(k), row ky: 9 taps, depth-1 prefetch on A-frags + weights ----
      s16x8 AH[2][3], AL[2][3], BH[2][2], BL[2][2];
      {
        const int rowoff = (ky * 20) * 40;
#pragma unroll
        for (int m = 0; m < 3; ++m) {
          AH[0][m] = *(const s16x8*)&c1hi[base0[m] + rowoff];
          AL[0][m] = *(const s16x8*)&c1lo[base0[m] + rowoff];
        }
        const size_t tb = (size_t)(ky * 9) * 65536 + (size_t)k * 32;
#pragma unroll
        for (int j = 0; j < 2; ++j) {
          BH[0][j] = *(const s16x8*)&whi[tb + boff[j]];
          BL[0][j] = *(const s16x8*)&wlo[tb + boff[j]];
        }
      }
#pragma unroll
      for (int kx = 0; kx < 9; ++kx) {
        const int cur = kx & 1, nxt = cur ^ 1;
        if (kx < 8) {
          const int rowoff = (ky * 20 + kx + 1) * 40;
#pragma unroll
          for (int m = 0; m < 3; ++m) {
            AH[nxt][m] = *(const s16x8*)&c1hi[base0[m] + rowoff];
            AL[nxt][m] = *(const s16x8*)&c1lo[base0[m] + rowoff];
          }
          const size_t tb = (size_t)(ky * 9 + kx + 1) * 65536 + (size_t)k * 32;
#pragma unroll
          for (int j = 0; j < 2; ++j) {
            BH[nxt][j] = *(const s16x8*)&whi[tb + boff[j]];
            BL[nxt][j] = *(const s16x8*)&wlo[tb + boff[j]];
          }
        }
#pragma unroll
        for (int m = 0; m < 3; ++m)
#pragma unroll
          for (int j = 0; j < 2; ++j)
            acc[m][j] = __builtin_amdgcn_mfma_f32_16x16x32_bf16(AH[cur][m], BH[cur][j], acc[m][j], 0, 0, 0);
#pragma unroll
        for (int m = 0; m < 3; ++m)
#pragma unroll
          for (int j = 0; j < 2; ++j)
            acc[m][j] = __builtin_amdgcn_mfma_f32_16x16x32_bf16(AL[cur][m], BH[cur][j], acc[m][j], 0, 0, 0);
#pragma unroll
        for (int m = 0; m < 3; ++m)
#pragma unroll
          for (int j = 0; j < 2; ++j)
            acc[m][j] = __builtin_amdgcn_mfma_f32_16x16x32_bf16(AH[cur][m], BL[cur][j], acc[m][j], 0, 0, 0);
      }
    }
    __syncthreads();  // all waves done reading chunk k
    if (doA) {
      store_c1(c1hi, c1lo, ci0, y0, accA0);
      if (has1) store_c1(c1hi, c1lo, ci0, y0 + 16, accA1);
    }
    __syncthreads();  // chunk k+1 visible
  }

  // ---- store: D col=lane&15, row=(lane>>4)*4+reg; xcaps[b][n][d] ----
#pragma unroll
  for (int m = 0; m < 3; ++m) {
#pragma unroll
    for (int jj = 0; jj < 4; ++jj) {
      const int pos = m * 16 + kg * 4 + jj;
      if (pos < 36) {
#pragma unroll
        for (int j = 0; j < 2; ++j) {
          const int co = con[j];
          const int n = (co & 31) * 36 + pos;
          xcaps[((size_t)b * 1152 + n) * 8 + (co >> 5)] = acc[m][j][jj] + bias[j];
        }
      }
    }
  }
}

// ---------------- fused u_hat + routing: block per (o,b) ----------------
__global__ __launch_bounds__(256) void routing_fused(const float* __restrict__ xcaps,
                                                     const float* __restrict__ W,
                                                     float* __restrict__ out) {
  const int o = blockIdx.x >> 8;
  const int b = blockIdx.x & 255;
  const int t = threadIdx.x;
  const int k = t & 15, ng = t >> 4;
  __shared__ float xs[1152 * 9];  // x[b] padded stride 8->9
  __shared__ double redA[256];
  __shared__ double redB[256];
  __shared__ float s_s[16];
  __shared__ float s_sv;
  __shared__ double s_f;

  {
    const float4* src = (const float4*)(xcaps + (size_t)b * 9216);
    for (int idx = t; idx < 2304; idx += 256) {
      float4 v = src[idx];
      const int n = idx >> 1, h = idx & 1;
      float* dst = &xs[n * 9 + h * 4];
      dst[0] = v.x; dst[1] = v.y; dst[2] = v.z; dst[3] = v.w;
    }
  }
  __syncthreads();

  const int n0 = ng * 72;
  float u[72];
  const float* wp = W + ((size_t)(n0 * 10 + o) * 16 + k) * 8;
#pragma unroll
  for (int i = 0; i < 72; ++i) {
    const float* wq = wp + (size_t)i * 1280;
    const float4 wa = *(const float4*)wq;
    const float4 wb = *(const float4*)(wq + 4);
    const float* xp = &xs[(n0 + i) * 9];
    float s = fmaf(wa.x, xp[0], 0.f);
    s = fmaf(wa.y, xp[1], s);
    s = fmaf(wa.z, xp[2], s);
    s = fmaf(wa.w, xp[3], s);
    s = fmaf(wb.x, xp[4], s);
    s = fmaf(wb.y, xp[5], s);
    s = fmaf(wb.z, xp[6], s);
    s = fmaf(wb.w, xp[7], s);
    u[i] = s;
  }

  // ---- pass 1: uniform c = 1/1152 ----
  double S = 0.0;
#pragma unroll
  for (int i = 0; i < 72; ++i) S += (double)u[i];
  redA[t] = S;
  __syncthreads();
  if (t < 16) {
    double tt = 0.0;
#pragma unroll
    for (int g = 0; g < 16; ++g) tt += redA[g * 16 + t];
    s_s[t] = (float)(tt * (double)(1.0f / 1152.0f));
  }
  __syncthreads();
  if (t == 0) {
    double sn = 0.0;
#pragma unroll
    for (int kk = 0; kk < 16; ++kk) sn += (double)s_s[kk] * (double)s_s[kk];
    const double f = sn / ((1.0 + sn) * sqrt(sn));
    double sv = 0.0;
#pragma unroll
    for (int kk = 0; kk < 16; ++kk) sv += (double)s_s[kk] * f;
    s_sv = (float)sv;
  }
  __syncthreads();
  const float sv1 = s_sv;

  // ---- pass 2: logits u*sv1 ----
  double E = 0.0, EU = 0.0;
#pragma unroll
  for (int i = 0; i < 72; ++i) {
    const float e = expf(u[i] * sv1);
    E += (double)e;
    EU += (double)e * (double)u[i];
  }
  redA[t] = E; redB[t] = EU;
  __syncthreads();
  if (t < 16) {
    double te = 0.0, tu = 0.0;
#pragma unroll
    for (int g = 0; g < 16; ++g) { te += redA[g * 16 + t]; tu += redB[g * 16 + t]; }
    s_s[t] = (float)(tu / te);
  }
  __syncthreads();
  if (t == 0) {
    double sn = 0.0;
#pragma unroll
    for (int kk = 0; kk < 16; ++kk) sn += (double)s_s[kk] * (double)s_s[kk];
    const double f = sn / ((1.0 + sn) * sqrt(sn));
    double sv = 0.0;
#pragma unroll
    for (int kk = 0; kk < 16; ++kk) sv += (double)s_s[kk] * f;
    s_sv = sv1 + (float)sv;
  }
  __syncthreads();
  const float sv12 = s_sv;

  // ---- pass 3 -> output ----
  E = 0.0; EU = 0.0;
#pragma unroll
  for (int i = 0; i < 72; ++i) {
    const float e = expf(u[i] * sv12);
    E += (double)e;
    EU += (double)e * (double)u[i];
  }
  redA[t] = E; redB[t] = EU;
  __syncthreads();
  if (t < 16) {
    double te = 0.0, tu = 0.0;
#pragma unroll
    for (int g = 0; g < 16; ++g) { te += redA[g * 16 + t]; tu += redB[g * 16 + t]; }
    s_s[t] = (float)(tu / te);
  }
  __syncthreads();
  if (t == 0) {
    double sn = 0.0;
#pragma unroll
    for (int kk = 0; kk < 16; ++kk) sn += (double)s_s[kk] * (double)s_s[kk];
    s_f = sn / ((1.0 + sn) * sqrt(sn));
  }
  __syncthreads();
  if (t < 16) out[b * 160 + o * 16 + t] = (float)((double)s_s[t] * s_f);
}

extern "C" void kernel_launch(void* const* d_in, const int* in_sizes, int n_in,
                              void* d_out, int out_size, void* d_ws, size_t ws_size,
                              hipStream_t stream) {
  const float* data = (const float*)d_in[0];
  const float* w1   = (const float*)d_in[1];
  const float* b1   = (const float*)d_in[2];
  const float* w2   = (const float*)d_in[3];
  const float* b2   = (const float*)d_in[4];
  const float* W    = (const float*)d_in[5];
  float* out = (float*)d_out;

  short* whi   = (short*)d_ws;            // 5,308,416 shorts
  short* wlo   = whi + 5308416;           // 5,308,416 shorts
  float* xcaps = (float*)(wlo + 5308416); // 2,359,296 floats

  prep_w2<<<256, 256, 0, stream>>>(w2, whi, wlo);
  conv2_mfma<<<256, 512, 0, stream>>>(data, w1, b1, whi, wlo, b2, xcaps);
  routing_fused<<<2560, 256, 0, stream>>>(xcaps, W, out);
}